// Round 11
// baseline (194.982 us; speedup 1.0000x reference)
//
#include <hip/hip_runtime.h>

#define NPTS 8192
#define DIM 128
#define NCLS 128
#define KSEL 17      // k+1 smallest define the threshold
#define RB   64      // rows per block = 4 waves x 16 (proven r5/r7/r10 TLP geometry)
#define NIT  16      // 32-col steps per segment (512/32)
#define CAPW 40      // per-row LDS candidate capacity
#define SEG  32      // per-(row,segment) scratch segment
#define NSEG 16      // column segments (512 cols each) -> grid 2048 = 6 blocks/CU (LDS-capped)
#define MBLK 1024    // merge blocks (8 rows each)
#define BIG 3.0e38f

typedef short bf16x8 __attribute__((ext_vector_type(8)));
typedef float f32x4 __attribute__((ext_vector_type(4)));

__device__ __forceinline__ unsigned short f2bf(float f) {
  unsigned int u = __float_as_uint(f);
  u += 0x7fffu + ((u >> 16) & 1u);   // round-to-nearest-even
  return (unsigned short)(u >> 16);
}

// order-preserving float <-> uint map (total order, exact inverse)
__device__ __forceinline__ unsigned flipF(float f) {
  unsigned u = __float_as_uint(f);
  return (u & 0x80000000u) ? ~u : (u | 0x80000000u);
}
__device__ __forceinline__ float unflipF(unsigned k) {
  unsigned u = (k & 0x80000000u) ? (k & 0x7fffffffu) : ~k;
  return __uint_as_float(u);
}

// exact KSEL-th smallest of the 512 values {e0..e7} x 64 lanes.
// all inputs >= 0 (encoded d2, flag stripped, or BIG) -> flipped keys have
// bit31 set; start descent at bit 30. Full precision. (verified r8: passed)
__device__ __forceinline__ float kth17_8(float e0, float e1, float e2, float e3,
                                         float e4, float e5, float e6, float e7) {
  const unsigned k0 = flipF(e0), k1 = flipF(e1), k2 = flipF(e2), k3 = flipF(e3);
  const unsigned k4 = flipF(e4), k5 = flipF(e5), k6 = flipF(e6), k7 = flipF(e7);
  unsigned ans = 0x80000000u;
  for (int bit = 30; bit >= 0; --bit) {
    unsigned mid = ans | (1u << bit);
    int cc = __popcll(__ballot(k0 < mid)) + __popcll(__ballot(k1 < mid)) +
             __popcll(__ballot(k2 < mid)) + __popcll(__ballot(k3 < mid)) +
             __popcll(__ballot(k4 < mid)) + __popcll(__ballot(k5 < mid)) +
             __popcll(__ballot(k6 < mid)) + __popcll(__ballot(k7 < mid));
    if (cc < KSEL) ans = mid;
  }
  return unflipF(ans);
}

// ---- prep: blocks 0..2047 build bf16 X (and -2X for the B operand) + exact
// norms; block 2048: class stats.
// f2bf(-2x) == -2*f2bf(x) exactly (x2 shifts exponent only), so A.B products
// are bit-identical to -2*(a.b); only the f32 accumulation order changes.
__global__ void prep(const float* __restrict__ X, const long long* __restrict__ targets,
                     unsigned short* __restrict__ Xb, unsigned short* __restrict__ Xb2,
                     float* __restrict__ sqv, int* __restrict__ tgt,
                     int* __restrict__ ccount, int* __restrict__ j0a,
                     int* __restrict__ j1a) {
  const int tid = threadIdx.x;
  if (blockIdx.x == 2048) {
    __shared__ int cc[NCLS], c0[NCLS], c1[NCLS];
    if (tid < NCLS) { cc[tid] = 0; c0[tid] = 0x7fffffff; c1[tid] = 0x7fffffff; }
    __syncthreads();
    for (int base = tid * 4; base < NPTS; base += 1024) {
      const long long* p = targets + base;
#pragma unroll
      for (int k = 0; k < 4; k++) {
        int c = (int)p[k];
        tgt[base + k] = c;
        atomicAdd(&cc[c], 1);
        atomicMin(&c0[c], base + k);
      }
    }
    __syncthreads();
    for (int base = tid * 4; base < NPTS; base += 1024) {
#pragma unroll
      for (int k = 0; k < 4; k++) {
        int c = tgt[base + k];
        if (base + k != c0[c]) atomicMin(&c1[c], base + k);
      }
    }
    __syncthreads();
    if (tid < NCLS) { ccount[tid] = cc[tid]; j0a[tid] = c0[tid]; j1a[tid] = c1[tid]; }
    return;
  }
  const int w = tid >> 6, lane = tid & 63;
  const int gw = blockIdx.x * 4 + w;
  const float* xr = X + (size_t)gw * DIM;
  float a = xr[lane], b = xr[lane + 64];
  Xb[(size_t)gw * DIM + lane] = f2bf(a);
  Xb[(size_t)gw * DIM + lane + 64] = f2bf(b);
  Xb2[(size_t)gw * DIM + lane] = f2bf(-2.0f * a);
  Xb2[(size_t)gw * DIM + lane + 64] = f2bf(-2.0f * b);
  float s = a * a + b * b;
#pragma unroll
  for (int off = 32; off; off >>= 1) s += __shfl_xor(s, off);
  if (lane == 0) sqv[gw] = s;
}

// ---- two-sweep kNN: r10 structure (64 rows/block, 16 rows/wave, DMA staging
// with pre-swizzled global source, acc-init val = sqj - 2*G) at NSEG=16:
// grid 2048 = 128 row-groups x 16 column-segments (512 cols). With the
// acc-init loop at 48 VGPR, occupancy is no longer register-forced — 27KB LDS
// admits 6 blocks/CU, so the doubled grid lifts steady-state waves/CU 16->24.
// (r2's identical split had no occupancy headroom — 84 VGPR then — and lost;
// r8's NSEG=16 bundled RB=128 + partial-line scr writes; both fixed here.)
// scr segments are written as FULL 128B lines (BIG padding) to avoid the
// partial-line RMW amplification suspected in r8 (WRITE 49MB on a 16MB scr).
__global__ __launch_bounds__(256, 4) void knn_main(
    const unsigned short* __restrict__ Xb, const unsigned short* __restrict__ Xb2,
    const float* __restrict__ sqv, const int* __restrict__ tgt,
    float* __restrict__ scr, int* __restrict__ cscr) {
  __shared__ __align__(16) unsigned short shB[2][4096];  // 2 x 8KB slab (DMA dest)
  __shared__ __align__(16) float shPub[RB * CAPW];       // 10KB: pool (8KB) / bufD overlay
  __shared__ int cntL[RB];

  const int tid = threadIdx.x;
  const int w = tid >> 6;
  const int lane = tid & 63;
  const int quad = lane >> 4;
  const int l16 = lane & 15;
  const int rg = blockIdx.x >> 4;
  const int seg16 = blockIdx.x & 15;
  const int rbase = rg * RB;
  const int cbase = seg16 * 512;

  const unsigned lmlt = (1u << l16) - 1;
  // LDS read offsets (XOR-swizzled), tile0; tile1 = +4096 (bit12, disjoint from XOR bits)
  int rdoff[4];
#pragma unroll
  for (int kb = 0; kb < 4; kb++)
    rdoff[kb] = (l16 * 256 + quad * 16 + kb * 64) ^ ((l16 & 7) << 4);

  // DMA source pre-swizzle: wave w stages dest granules [w*128, w*128+128)
  // in two 64-lane issues; lane's source granule = G ^ ((G>>4)&7).
  const int g0 = w * 128 + lane;
  const int g1 = w * 128 + 64 + lane;
  const int soff0 = (g0 ^ ((g0 >> 4) & 7)) * 16;   // byte offsets into the slab
  const int soff1 = (g1 ^ ((g1 >> 4) & 7)) * 16;
  const int ldst0 = (w * 128) * 16;                // wave-uniform LDS byte bases
  const int ldst1 = (w * 128 + 64) * 16;

  const char* gslab0 = (const char*)(Xb2) + (size_t)cbase * DIM * 2;
  auto stage = [&](int buf, int j) {
    const char* src = gslab0 + (size_t)j * 8192;
    __builtin_amdgcn_global_load_lds((const unsigned int*)(src + soff0),
                                     (unsigned int*)((char*)&shB[buf][0] + ldst0),
                                     16, 0, 0);
    __builtin_amdgcn_global_load_lds((const unsigned int*)(src + soff1),
                                     (unsigned int*)((char*)&shB[buf][0] + ldst1),
                                     16, 0, 0);
  };

  // A fragments: wave's 16 rows. 16x16x32 bf16: A[m=l16][k=quad*8+j]
  bf16x8 afrag[4];
  {
    const unsigned short* arow = Xb + (size_t)(rbase + w * 16 + l16) * DIM + quad * 8;
#pragma unroll
    for (int kb = 0; kb < 4; kb++) afrag[kb] = *(const bf16x8*)(arow + kb * 32);
  }
  float sqi[4]; int ti[4];
#pragma unroll
  for (int r = 0; r < 4; r++) {
    int rr = rbase + w * 16 + quad * 4 + r;
    sqi[r] = sqv[rr]; ti[r] = tgt[rr];
  }
  // wave-uniform diagonal 16-col tile (0..31) or -1
  int tdw;
  {
    int d = rbase + w * 16 - cbase;
    tdw = (d >= 0 && d < 512) ? (d >> 4) : -1;
  }

  const float* sqp = sqv + cbase + l16;
  const int*   tgp = tgt + cbase + l16;

  // ---- sweep 1: min-2 per (row, l16-class); 32 cols per step
  float m1[4], m2[4];
#pragma unroll
  for (int r = 0; r < 4; r++) { m1[r] = BIG; m2[r] = BIG; }
  stage(0, 0);
  __syncthreads();   // compiler drains vmcnt before s_barrier
  for (int j = 0; j < NIT; j++) {
    const int jn = (j + 1 < NIT) ? j + 1 : 0;
    stage((j & 1) ^ 1, jn);
    const float sq0 = sqp[j * 32], sq1 = sqp[j * 32 + 16];
    const char* lb = (const char*)&shB[j & 1][0];
    f32x4 a0 = {sq0, sq0, sq0, sq0}, a1 = {sq1, sq1, sq1, sq1};
    {
      bf16x8 b[4];
#pragma unroll
      for (int kb = 0; kb < 4; kb++) b[kb] = *(const bf16x8*)(lb + rdoff[kb]);
#pragma unroll
      for (int kb = 0; kb < 4; kb++)
        a0 = __builtin_amdgcn_mfma_f32_16x16x32_bf16(afrag[kb], b[kb], a0, 0, 0, 0);
    }
    {
      bf16x8 b[4];
#pragma unroll
      for (int kb = 0; kb < 4; kb++) b[kb] = *(const bf16x8*)(lb + rdoff[kb] + 4096);
#pragma unroll
      for (int kb = 0; kb < 4; kb++)
        a1 = __builtin_amdgcn_mfma_f32_16x16x32_bf16(afrag[kb], b[kb], a1, 0, 0, 0);
    }
    float v0[4], v1[4];
#pragma unroll
    for (int r = 0; r < 4; r++) { v0[r] = a0[r]; v1[r] = a1[r]; }
    if ((unsigned)(tdw - 2 * j) < 2u) {
#pragma unroll
      for (int r = 0; r < 4; r++) {
        if (2 * j == tdw && l16 == quad * 4 + r) v0[r] = BIG;
        if (2 * j + 1 == tdw && l16 == quad * 4 + r) v1[r] = BIG;
      }
    }
#pragma unroll
    for (int r = 0; r < 4; r++) {
      m2[r] = __builtin_amdgcn_fmed3f(m1[r], m2[r], v0[r]);
      m1[r] = fminf(m1[r], v0[r]);
      m2[r] = __builtin_amdgcn_fmed3f(m1[r], m2[r], v1[r]);
      m1[r] = fminf(m1[r], v1[r]);
    }
    __syncthreads();
  }
  // NOTE: sweep-1's last iteration re-staged slab 0 into shB[0] and synced.

  // ---- U[row]: publish min-2 pool (32 values/row), truncated radix-select.
  // Pool rows are wave-local (written and read only by wave w).
#pragma unroll
  for (int r = 0; r < 4; r++) {
    const int row = w * 16 + quad * 4 + r;
    shPub[row * 32 + l16 * 2] = m1[r];
    shPub[row * 32 + l16 * 2 + 1] = m2[r];
  }
  float Ur[4];
  for (int rp = 0; rp < 16; rp += 2) {   // two rows interleaved
    const int li = lane & 31;
    const unsigned ka  = (lane < 32) ? flipF(shPub[(w * 16 + rp) * 32 + li]) : 0xFFFFFFFFu;
    const unsigned kb2 = (lane < 32) ? flipF(shPub[(w * 16 + rp + 1) * 32 + li]) : 0xFFFFFFFFu;
    unsigned ansA = 0u, ansB = 0u;
    for (int bit = 31; bit >= 14; --bit) {
      const unsigned mA = ansA | (1u << bit), mB = ansB | (1u << bit);
      const int ca = __popcll(__ballot(ka < mA));
      const int cb = __popcll(__ballot(kb2 < mB));
      if (ca < KSEL) ansA = mA;
      if (cb < KSEL) ansB = mB;
    }
    const float ua = unflipF(ansA | 0x3FFFu), ub = unflipF(ansB | 0x3FFFu);
#pragma unroll
    for (int r = 0; r < 4; r++) {
      const int myrow = quad * 4 + r;
      if (myrow == rp) Ur[r] = ua;
      if (myrow == rp + 1) Ur[r] = ub;
    }
  }
  __syncthreads();   // bufD overlay: wave w's appends overlap other waves' pool bytes

  // ---- sweep 2: append val <= U (encode d2 = val + sqi, flag in sign bit).
  float* bufD = shPub;
  int cntr[4] = {0, 0, 0, 0};
  for (int j = 0; j < NIT; j++) {
    const int jn = (j + 1 < NIT) ? j + 1 : 0;
    stage((j & 1) ^ 1, jn);
    const float sq0 = sqp[j * 32], sq1 = sqp[j * 32 + 16];
    const int tj0 = tgp[j * 32], tj1 = tgp[j * 32 + 16];
    const char* lb = (const char*)&shB[j & 1][0];
    f32x4 a0 = {sq0, sq0, sq0, sq0}, a1 = {sq1, sq1, sq1, sq1};
    {
      bf16x8 b[4];
#pragma unroll
      for (int kb = 0; kb < 4; kb++) b[kb] = *(const bf16x8*)(lb + rdoff[kb]);
#pragma unroll
      for (int kb = 0; kb < 4; kb++)
        a0 = __builtin_amdgcn_mfma_f32_16x16x32_bf16(afrag[kb], b[kb], a0, 0, 0, 0);
    }
    {
      bf16x8 b[4];
#pragma unroll
      for (int kb = 0; kb < 4; kb++) b[kb] = *(const bf16x8*)(lb + rdoff[kb] + 4096);
#pragma unroll
      for (int kb = 0; kb < 4; kb++)
        a1 = __builtin_amdgcn_mfma_f32_16x16x32_bf16(afrag[kb], b[kb], a1, 0, 0, 0);
    }
    float v0[4], v1[4];
#pragma unroll
    for (int r = 0; r < 4; r++) { v0[r] = a0[r]; v1[r] = a1[r]; }
    if ((unsigned)(tdw - 2 * j) < 2u) {
#pragma unroll
      for (int r = 0; r < 4; r++) {
        if (2 * j == tdw && l16 == quad * 4 + r) v0[r] = BIG;
        if (2 * j + 1 == tdw && l16 == quad * 4 + r) v1[r] = BIG;
      }
    }
#pragma unroll
    for (int r = 0; r < 4; r++) {
      {
        const bool p = (v0[r] <= Ur[r]);
        const unsigned long long bal = __ballot(p);
        if (bal) {
          const unsigned qm = (unsigned)(bal >> (quad << 4)) & 0xFFFFu;
          const int pos = cntr[r] + __popc(qm & lmlt);
          if (p && pos < CAPW) {
            unsigned enc = __float_as_uint(fmaxf(v0[r] + sqi[r], 0.0f));
            if (tj0 == ti[r]) enc |= 0x80000000u;
            bufD[(w * 16 + quad * 4 + r) * CAPW + pos] = __uint_as_float(enc);
          }
          cntr[r] += __popc(qm);   // identical across the quad's 16 lanes
        }
      }
      {
        const bool p = (v1[r] <= Ur[r]);
        const unsigned long long bal = __ballot(p);
        if (bal) {
          const unsigned qm = (unsigned)(bal >> (quad << 4)) & 0xFFFFu;
          const int pos = cntr[r] + __popc(qm & lmlt);
          if (p && pos < CAPW) {
            unsigned enc = __float_as_uint(fmaxf(v1[r] + sqi[r], 0.0f));
            if (tj1 == ti[r]) enc |= 0x80000000u;
            bufD[(w * 16 + quad * 4 + r) * CAPW + pos] = __uint_as_float(enc);
          }
          cntr[r] += __popc(qm);
        }
      }
    }
    __syncthreads();
  }
#pragma unroll
  for (int r = 0; r < 4; r++)
    if (l16 == 0) cntL[w * 16 + quad * 4 + r] = cntr[r];
  __syncthreads();

  // ---- finalize (wave-local rows): raw copy (common) or exact 17-extract
  // (rare). Segments are written as FULL 128B lines (BIG padding) so L2 never
  // does partial-line RMW on scr.
  for (int rl = 0; rl < 16; rl++) {
    const int row = w * 16 + rl;
    const int grow = rbase + row;
    const int tot = cntL[row];
    float* srow = scr + (size_t)grow * (NSEG * SEG) + seg16 * SEG;
    if (tot <= SEG) {
      if (lane < SEG) srow[lane] = (lane < tot) ? bufD[row * CAPW + lane] : BIG;
      if (lane == 0) cscr[grow * NSEG + seg16] = tot;
    } else {
      const int n = min(tot, CAPW);
      float e = BIG; int m = 0;
      if (lane < n) {
        unsigned u = __float_as_uint(bufD[row * CAPW + lane]);
        m = (int)(u >> 31); e = __uint_as_float(u & 0x7fffffffu);
      }
      for (int round = 0; round < KSEL; round++) {
        float vv = e; int idx = lane;
#pragma unroll
        for (int off = 32; off; off >>= 1) {
          float ov = __shfl_xor(vv, off);
          int   oi = __shfl_xor(idx, off);
          if (ov < vv || (ov == vv && oi < idx)) { vv = ov; idx = oi; }
        }
        if (idx == lane) {
          unsigned ub = __float_as_uint(e);
          if (m) ub |= 0x80000000u;
          srow[round] = __uint_as_float(ub);
          e = BIG;
        }
      }
      if (lane >= KSEL && lane < SEG) srow[lane] = BIG;   // full-line pad
      if (lane == 0) cscr[grow * NSEG + seg16] = KSEL;
    }
  }
}

// ---- per-row merge of 16 segment-lists (<=512 candidates, 8 per lane) + loss
// epilogue. Structure verified in r8 (passed, absmax 0.03125). Standalone —
// NO device fences (r9 lesson: per-block __threadfence cost ~60us).
__global__ __launch_bounds__(256) void knn_merge(
    const float* __restrict__ scr, const int* __restrict__ cscr,
    const float* __restrict__ sqv, const int* __restrict__ tgt,
    const int* __restrict__ ccount, const int* __restrict__ j0a,
    const int* __restrict__ j1a, const float* __restrict__ X32,
    float* __restrict__ pacc) {
  __shared__ float blockAcc[4];
  const int tid = threadIdx.x;
  const int w = tid >> 6;
  const int lane = tid & 63;
  if (tid < 4) blockAcc[tid] = 0.0f;
  __syncthreads();
  for (int ri = 0; ri < 2; ri++) {
    const int grow = blockIdx.x * 8 + w * 2 + ri;
    const float* srow = scr + (size_t)grow * (NSEG * SEG);
    const int h = lane >> 5, li = lane & 31;
    float e[8]; int mm[8];
#pragma unroll
    for (int j = 0; j < 8; j++) {
      const int seg = j * 2 + h;
      const int cj = cscr[grow * NSEG + seg];
      if (li < cj) {
        unsigned u = __float_as_uint(srow[seg * SEG + li]);
        mm[j] = (int)(u >> 31); e[j] = __uint_as_float(u & 0x7fffffffu);
      } else { e[j] = BIG; mm[j] = 0; }
    }
    const float t17 = kth17_8(e[0], e[1], e[2], e[3], e[4], e[5], e[6], e[7]);
    float pls = 0.0f, nls = 0.0f; int cp = 0, cn = 0;
#pragma unroll
    for (int j = 0; j < 8; j++) {
      const bool s = (e[j] < t17);                        // strict, matches reference
      const float x = s ? expf(-sqrtf(fmaxf(e[j], 1e-12f))) : 0.0f;
      if (mm[j]) { pls += x; cp += (int)s; }
      else       { nls += x; cn += (int)s; }
    }
    int cpn = cp * 65536 + cn;
#pragma unroll
    for (int off = 32; off; off >>= 1) {
      pls += __shfl_xor(pls, off); nls += __shfl_xor(nls, off);
      cpn += __shfl_xor(cpn, off);
    }
    const int cpt = cpn >> 16, cnt_ = cpn & 0xffff;
    const int c = tgt[grow];
    const int ncl = ccount[c];
    const bool valid = (ncl > 1) && (ncl < NPTS);
    if (valid) {
      float pos_eff;
      if (cpt == 0) {
        const int jf = (grow == j0a[c]) ? j1a[c] : j0a[c];
        const float* xi = X32 + (size_t)grow * DIM;
        const float* xj = X32 + (size_t)jf * DIM;
        float pp = xi[lane] * xj[lane] + xi[lane + 64] * xj[lane + 64];
#pragma unroll
        for (int off = 32; off; off >>= 1) pp += __shfl_xor(pp, off);
        const float fb2 = sqv[grow] + sqv[jf] - 2.0f * pp;
        pos_eff = expf(-sqrtf(fmaxf(fb2, 1e-12f)));
      } else {
        pos_eff = pls;
      }
      if (lane == 0) {
        const float loss_i = -logf(pos_eff / (pos_eff + nls));
        const int cpa = (cpt == 0) ? 1 : cpt;
        atomicAdd(&blockAcc[0], loss_i);
        atomicAdd(&blockAcc[1], (cpa > cnt_) ? 1.0f : 0.0f);
        atomicAdd(&blockAcc[2], (float)cpt);
        atomicAdd(&blockAcc[3], (float)cnt_);
      }
    }
  }
  __syncthreads();
  if (tid < 4) pacc[blockIdx.x * 4 + tid] = blockAcc[tid];
}

// ---- final reduction: 1 block sums 1024 x 4 partials, writes out
__global__ void fin(const float* __restrict__ pacc, float* __restrict__ out) {
  __shared__ float red[256];
  const int tid = threadIdx.x;
  const int c = tid & 3, b0 = tid >> 2;
  float s = 0.0f;
  for (int b = b0; b < MBLK; b += 64) s += pacc[b * 4 + c];
  red[tid] = s;
  __syncthreads();
  if (tid < 4) {
    float t = 0.0f;
    for (int i = tid; i < 256; i += 4) t += red[i];
    out[tid] = t * (1.0f / (float)NPTS);
  }
}

extern "C" void kernel_launch(void* const* d_in, const int* in_sizes, int n_in,
                              void* d_out, int out_size, void* d_ws, size_t ws_size,
                              hipStream_t stream) {
  const float* X = (const float*)d_in[0];
  const long long* targets = (const long long*)d_in[1];
  float* out = (float*)d_out;

  char* ws = (char*)d_ws;
  unsigned short* Xb  = (unsigned short*)ws;                       // 2 MiB
  unsigned short* Xb2 = (unsigned short*)(ws + (2u << 20));        // 2 MiB (-2x)
  float* sqv    = (float*)   (ws + (4u << 20));                    // 32 KiB
  int*   tgt    = (int*)     (ws + (4u << 20) + (32u << 10));      // 32 KiB
  int*   ccount = (int*)     (ws + (4u << 20) + (64u << 10));      // 512 B
  int*   j0a    = (int*)     (ws + (4u << 20) + (65u << 10));      // 512 B
  int*   j1a    = (int*)     (ws + (4u << 20) + (66u << 10));      // 512 B
  float* pacc   = (float*)   (ws + (4u << 20) + (68u << 10));      // 16 KiB (1024 x 4)
  float* scr = (float*)(ws + (4u << 20) + (128u << 10));           // 8192*16*SEG*4 = 16 MiB
  int* cscr  = (int*)  (ws + (4u << 20) + (128u << 10) +
                        (size_t)NPTS * NSEG * SEG * 4);            // 512 KiB

  prep<<<2049, 256, 0, stream>>>(X, targets, Xb, Xb2, sqv, tgt, ccount, j0a, j1a);
  knn_main<<<2048, 256, 0, stream>>>(Xb, Xb2, sqv, tgt, scr, cscr);
  knn_merge<<<MBLK, 256, 0, stream>>>(scr, cscr, sqv, tgt, ccount, j0a, j1a, X, pacc);
  fin<<<1, 256, 0, stream>>>(pacc, out);
}

// Round 12
// 172.091 us; speedup vs baseline: 1.1330x; 1.1330x over previous
//
#include <hip/hip_runtime.h>

#define NPTS 8192
#define DIM 128
#define NCLS 128
#define KSEL 17      // k+1 smallest define the threshold
#define RB   64      // rows per block = 4 waves x 16 (proven r5/r7/r10 TLP geometry)
#define NIT  32      // 32-col steps per eighth (1024/32)
#define CAPW 40      // per-row LDS candidate capacity
#define SEG  32      // per-(row,eighth) scratch segment
#define NSEG 8       // column eighths
#define MBLK 1024    // merge blocks (8 rows each)
#define BIG 3.0e38f

typedef short bf16x8 __attribute__((ext_vector_type(8)));
typedef float f32x4 __attribute__((ext_vector_type(4)));

__device__ __forceinline__ unsigned short f2bf(float f) {
  unsigned int u = __float_as_uint(f);
  u += 0x7fffu + ((u >> 16) & 1u);   // round-to-nearest-even
  return (unsigned short)(u >> 16);
}

// order-preserving float <-> uint map (total order, exact inverse)
__device__ __forceinline__ unsigned flipF(float f) {
  unsigned u = __float_as_uint(f);
  return (u & 0x80000000u) ? ~u : (u | 0x80000000u);
}
__device__ __forceinline__ float unflipF(unsigned k) {
  unsigned u = (k & 0x80000000u) ? (k & 0x7fffffffu) : ~k;
  return __uint_as_float(u);
}

// exact KSEL-th smallest of the 256 values {a,b,c,d} x 64 lanes.
// all inputs >= 0 (encoded d2, flag stripped, or BIG) -> flipped keys have
// bit31 set; start descent at bit 30. (proven r1/r4-r7/r9/r10)
__device__ __forceinline__ float kth17_4(float a, float b, float c, float d) {
  const unsigned ka = flipF(a), kb = flipF(b), kc = flipF(c), kd = flipF(d);
  unsigned ans = 0x80000000u;
  for (int bit = 30; bit >= 0; --bit) {
    unsigned mid = ans | (1u << bit);
    int cc = __popcll(__ballot(ka < mid)) + __popcll(__ballot(kb < mid)) +
             __popcll(__ballot(kc < mid)) + __popcll(__ballot(kd < mid));
    if (cc < KSEL) ans = mid;
  }
  return unflipF(ans);
}

// ---- prep: blocks 0..2047 build bf16 X (and -2X for the B operand) + exact
// norms; block 2048: class stats.
// f2bf(-2x) == -2*f2bf(x) exactly (x2 shifts exponent only), so A.B products
// are bit-identical to -2*(a.b); only the f32 accumulation order changes.
__global__ void prep(const float* __restrict__ X, const long long* __restrict__ targets,
                     unsigned short* __restrict__ Xb, unsigned short* __restrict__ Xb2,
                     float* __restrict__ sqv, int* __restrict__ tgt,
                     int* __restrict__ ccount, int* __restrict__ j0a,
                     int* __restrict__ j1a) {
  const int tid = threadIdx.x;
  if (blockIdx.x == 2048) {
    __shared__ int cc[NCLS], c0[NCLS], c1[NCLS];
    if (tid < NCLS) { cc[tid] = 0; c0[tid] = 0x7fffffff; c1[tid] = 0x7fffffff; }
    __syncthreads();
    for (int base = tid * 4; base < NPTS; base += 1024) {
      const long long* p = targets + base;
#pragma unroll
      for (int k = 0; k < 4; k++) {
        int c = (int)p[k];
        tgt[base + k] = c;
        atomicAdd(&cc[c], 1);
        atomicMin(&c0[c], base + k);
      }
    }
    __syncthreads();
    for (int base = tid * 4; base < NPTS; base += 1024) {
#pragma unroll
      for (int k = 0; k < 4; k++) {
        int c = tgt[base + k];
        if (base + k != c0[c]) atomicMin(&c1[c], base + k);
      }
    }
    __syncthreads();
    if (tid < NCLS) { ccount[tid] = cc[tid]; j0a[tid] = c0[tid]; j1a[tid] = c1[tid]; }
    return;
  }
  const int w = tid >> 6, lane = tid & 63;
  const int gw = blockIdx.x * 4 + w;
  const float* xr = X + (size_t)gw * DIM;
  float a = xr[lane], b = xr[lane + 64];
  Xb[(size_t)gw * DIM + lane] = f2bf(a);
  Xb[(size_t)gw * DIM + lane + 64] = f2bf(b);
  Xb2[(size_t)gw * DIM + lane] = f2bf(-2.0f * a);
  Xb2[(size_t)gw * DIM + lane + 64] = f2bf(-2.0f * b);
  float s = a * a + b * b;
#pragma unroll
  for (int off = 32; off; off >>= 1) s += __shfl_xor(s, off);
  if (lane == 0) sqv[gw] = s;
}

// ---- two-sweep kNN: r7 structure (64 rows/block, 16 rows/wave, 4 blocks/CU,
// DMA staging with pre-swizzled global source) + accumulator-init trick (r9):
// B operand comes from Xb2 = bf16(-2x) and acc inits to {sqj,...}, so the MFMA
// chain directly yields val = sqj - 2*G — no per-lane fmafs in the epilogues.
// Sweep-1 min-2/lane (pool 32/row); U = truncated-radix 17th of pool (upper
// bound of the eighth's true 17th). val-ordering is sqi-invariant per row.
__global__ __launch_bounds__(256, 4) void knn_main(
    const unsigned short* __restrict__ Xb, const unsigned short* __restrict__ Xb2,
    const float* __restrict__ sqv, const int* __restrict__ tgt,
    float* __restrict__ scr, int* __restrict__ cscr) {
  __shared__ __align__(16) unsigned short shB[2][4096];  // 2 x 8KB slab (DMA dest)
  __shared__ __align__(16) float shPub[RB * CAPW];       // 10KB: pool (8KB) / bufD overlay
  __shared__ int cntL[RB];

  const int tid = threadIdx.x;
  const int w = tid >> 6;
  const int lane = tid & 63;
  const int quad = lane >> 4;
  const int l16 = lane & 15;
  const int rg = blockIdx.x >> 3;
  const int eighth = blockIdx.x & 7;
  const int rbase = rg * RB;
  const int cbase = eighth * 1024;

  const unsigned lmlt = (1u << l16) - 1;
  // LDS read offsets (XOR-swizzled), tile0; tile1 = +4096 (bit12, disjoint from XOR bits)
  int rdoff[4];
#pragma unroll
  for (int kb = 0; kb < 4; kb++)
    rdoff[kb] = (l16 * 256 + quad * 16 + kb * 64) ^ ((l16 & 7) << 4);

  // DMA source pre-swizzle: wave w stages dest granules [w*128, w*128+128)
  // in two 64-lane issues; lane's source granule = G ^ ((G>>4)&7).
  const int g0 = w * 128 + lane;
  const int g1 = w * 128 + 64 + lane;
  const int soff0 = (g0 ^ ((g0 >> 4) & 7)) * 16;   // byte offsets into the slab
  const int soff1 = (g1 ^ ((g1 >> 4) & 7)) * 16;
  const int ldst0 = (w * 128) * 16;                // wave-uniform LDS byte bases
  const int ldst1 = (w * 128 + 64) * 16;

  const char* gslab0 = (const char*)(Xb2) + (size_t)cbase * DIM * 2;
  auto stage = [&](int buf, int j) {
    const char* src = gslab0 + (size_t)j * 8192;
    __builtin_amdgcn_global_load_lds((const unsigned int*)(src + soff0),
                                     (unsigned int*)((char*)&shB[buf][0] + ldst0),
                                     16, 0, 0);
    __builtin_amdgcn_global_load_lds((const unsigned int*)(src + soff1),
                                     (unsigned int*)((char*)&shB[buf][0] + ldst1),
                                     16, 0, 0);
  };

  // A fragments: wave's 16 rows. 16x16x32 bf16: A[m=l16][k=quad*8+j]
  bf16x8 afrag[4];
  {
    const unsigned short* arow = Xb + (size_t)(rbase + w * 16 + l16) * DIM + quad * 8;
#pragma unroll
    for (int kb = 0; kb < 4; kb++) afrag[kb] = *(const bf16x8*)(arow + kb * 32);
  }
  float sqi[4]; int ti[4];
#pragma unroll
  for (int r = 0; r < 4; r++) {
    int rr = rbase + w * 16 + quad * 4 + r;
    sqi[r] = sqv[rr]; ti[r] = tgt[rr];
  }
  // wave-uniform diagonal 16-col tile (0..63) or -1
  int tdw;
  {
    int d = rbase + w * 16 - cbase;
    tdw = (d >= 0 && d < 1024) ? (d >> 4) : -1;
  }

  const float* sqp = sqv + cbase + l16;
  const int*   tgp = tgt + cbase + l16;

  // ---- sweep 1: min-2 per (row, l16-class); 32 cols per step
  float m1[4], m2[4];
#pragma unroll
  for (int r = 0; r < 4; r++) { m1[r] = BIG; m2[r] = BIG; }
  stage(0, 0);
  __syncthreads();   // compiler drains vmcnt before s_barrier
  for (int j = 0; j < NIT; j++) {
    const int jn = (j + 1 < NIT) ? j + 1 : 0;
    stage((j & 1) ^ 1, jn);
    const float sq0 = sqp[j * 32], sq1 = sqp[j * 32 + 16];
    const char* lb = (const char*)&shB[j & 1][0];
    f32x4 a0 = {sq0, sq0, sq0, sq0}, a1 = {sq1, sq1, sq1, sq1};
    {
      bf16x8 b[4];
#pragma unroll
      for (int kb = 0; kb < 4; kb++) b[kb] = *(const bf16x8*)(lb + rdoff[kb]);
#pragma unroll
      for (int kb = 0; kb < 4; kb++)
        a0 = __builtin_amdgcn_mfma_f32_16x16x32_bf16(afrag[kb], b[kb], a0, 0, 0, 0);
    }
    {
      bf16x8 b[4];
#pragma unroll
      for (int kb = 0; kb < 4; kb++) b[kb] = *(const bf16x8*)(lb + rdoff[kb] + 4096);
#pragma unroll
      for (int kb = 0; kb < 4; kb++)
        a1 = __builtin_amdgcn_mfma_f32_16x16x32_bf16(afrag[kb], b[kb], a1, 0, 0, 0);
    }
    float v0[4], v1[4];
#pragma unroll
    for (int r = 0; r < 4; r++) { v0[r] = a0[r]; v1[r] = a1[r]; }
    if ((unsigned)(tdw - 2 * j) < 2u) {
#pragma unroll
      for (int r = 0; r < 4; r++) {
        if (2 * j == tdw && l16 == quad * 4 + r) v0[r] = BIG;
        if (2 * j + 1 == tdw && l16 == quad * 4 + r) v1[r] = BIG;
      }
    }
#pragma unroll
    for (int r = 0; r < 4; r++) {
      m2[r] = __builtin_amdgcn_fmed3f(m1[r], m2[r], v0[r]);
      m1[r] = fminf(m1[r], v0[r]);
      m2[r] = __builtin_amdgcn_fmed3f(m1[r], m2[r], v1[r]);
      m1[r] = fminf(m1[r], v1[r]);
    }
    __syncthreads();
  }
  // NOTE: sweep-1's last iteration re-staged slab 0 into shB[0] and synced.

  // ---- U[row]: publish min-2 pool (32 values/row), truncated radix-select.
  // Pool rows are wave-local (written and read only by wave w).
#pragma unroll
  for (int r = 0; r < 4; r++) {
    const int row = w * 16 + quad * 4 + r;
    shPub[row * 32 + l16 * 2] = m1[r];
    shPub[row * 32 + l16 * 2 + 1] = m2[r];
  }
  float Ur[4];
  for (int rp = 0; rp < 16; rp += 2) {   // two rows interleaved
    const int li = lane & 31;
    const unsigned ka  = (lane < 32) ? flipF(shPub[(w * 16 + rp) * 32 + li]) : 0xFFFFFFFFu;
    const unsigned kb2 = (lane < 32) ? flipF(shPub[(w * 16 + rp + 1) * 32 + li]) : 0xFFFFFFFFu;
    unsigned ansA = 0u, ansB = 0u;
    for (int bit = 31; bit >= 14; --bit) {
      const unsigned mA = ansA | (1u << bit), mB = ansB | (1u << bit);
      const int ca = __popcll(__ballot(ka < mA));
      const int cb = __popcll(__ballot(kb2 < mB));
      if (ca < KSEL) ansA = mA;
      if (cb < KSEL) ansB = mB;
    }
    const float ua = unflipF(ansA | 0x3FFFu), ub = unflipF(ansB | 0x3FFFu);
#pragma unroll
    for (int r = 0; r < 4; r++) {
      const int myrow = quad * 4 + r;
      if (myrow == rp) Ur[r] = ua;
      if (myrow == rp + 1) Ur[r] = ub;
    }
  }
  __syncthreads();   // bufD overlay: wave w's appends overlap other waves' pool bytes

  // ---- sweep 2: append val <= U (encode d2 = val + sqi, flag in sign bit).
  float* bufD = shPub;
  int cntr[4] = {0, 0, 0, 0};
  for (int j = 0; j < NIT; j++) {
    const int jn = (j + 1 < NIT) ? j + 1 : 0;
    stage((j & 1) ^ 1, jn);
    const float sq0 = sqp[j * 32], sq1 = sqp[j * 32 + 16];
    const int tj0 = tgp[j * 32], tj1 = tgp[j * 32 + 16];
    const char* lb = (const char*)&shB[j & 1][0];
    f32x4 a0 = {sq0, sq0, sq0, sq0}, a1 = {sq1, sq1, sq1, sq1};
    {
      bf16x8 b[4];
#pragma unroll
      for (int kb = 0; kb < 4; kb++) b[kb] = *(const bf16x8*)(lb + rdoff[kb]);
#pragma unroll
      for (int kb = 0; kb < 4; kb++)
        a0 = __builtin_amdgcn_mfma_f32_16x16x32_bf16(afrag[kb], b[kb], a0, 0, 0, 0);
    }
    {
      bf16x8 b[4];
#pragma unroll
      for (int kb = 0; kb < 4; kb++) b[kb] = *(const bf16x8*)(lb + rdoff[kb] + 4096);
#pragma unroll
      for (int kb = 0; kb < 4; kb++)
        a1 = __builtin_amdgcn_mfma_f32_16x16x32_bf16(afrag[kb], b[kb], a1, 0, 0, 0);
    }
    float v0[4], v1[4];
#pragma unroll
    for (int r = 0; r < 4; r++) { v0[r] = a0[r]; v1[r] = a1[r]; }
    if ((unsigned)(tdw - 2 * j) < 2u) {
#pragma unroll
      for (int r = 0; r < 4; r++) {
        if (2 * j == tdw && l16 == quad * 4 + r) v0[r] = BIG;
        if (2 * j + 1 == tdw && l16 == quad * 4 + r) v1[r] = BIG;
      }
    }
#pragma unroll
    for (int r = 0; r < 4; r++) {
      {
        const bool p = (v0[r] <= Ur[r]);
        const unsigned long long bal = __ballot(p);
        if (bal) {
          const unsigned qm = (unsigned)(bal >> (quad << 4)) & 0xFFFFu;
          const int pos = cntr[r] + __popc(qm & lmlt);
          if (p && pos < CAPW) {
            unsigned enc = __float_as_uint(fmaxf(v0[r] + sqi[r], 0.0f));
            if (tj0 == ti[r]) enc |= 0x80000000u;
            bufD[(w * 16 + quad * 4 + r) * CAPW + pos] = __uint_as_float(enc);
          }
          cntr[r] += __popc(qm);   // identical across the quad's 16 lanes
        }
      }
      {
        const bool p = (v1[r] <= Ur[r]);
        const unsigned long long bal = __ballot(p);
        if (bal) {
          const unsigned qm = (unsigned)(bal >> (quad << 4)) & 0xFFFFu;
          const int pos = cntr[r] + __popc(qm & lmlt);
          if (p && pos < CAPW) {
            unsigned enc = __float_as_uint(fmaxf(v1[r] + sqi[r], 0.0f));
            if (tj1 == ti[r]) enc |= 0x80000000u;
            bufD[(w * 16 + quad * 4 + r) * CAPW + pos] = __uint_as_float(enc);
          }
          cntr[r] += __popc(qm);
        }
      }
    }
    __syncthreads();
  }
#pragma unroll
  for (int r = 0; r < 4; r++)
    if (l16 == 0) cntL[w * 16 + quad * 4 + r] = cntr[r];
  __syncthreads();

  // ---- finalize (wave-local rows): raw copy (common) or exact 17-extract (rare)
  for (int rl = 0; rl < 16; rl++) {
    const int row = w * 16 + rl;
    const int grow = rbase + row;
    const int tot = cntL[row];
    float* srow = scr + (size_t)grow * (NSEG * SEG) + eighth * SEG;
    if (tot <= SEG) {
      if (lane < tot) srow[lane] = bufD[row * CAPW + lane];
      if (lane == 0) cscr[grow * NSEG + eighth] = tot;
    } else {
      const int n = min(tot, CAPW);
      float e = BIG; int m = 0;
      if (lane < n) {
        unsigned u = __float_as_uint(bufD[row * CAPW + lane]);
        m = (int)(u >> 31); e = __uint_as_float(u & 0x7fffffffu);
      }
      for (int round = 0; round < KSEL; round++) {
        float vv = e; int idx = lane;
#pragma unroll
        for (int off = 32; off; off >>= 1) {
          float ov = __shfl_xor(vv, off);
          int   oi = __shfl_xor(idx, off);
          if (ov < vv || (ov == vv && oi < idx)) { vv = ov; idx = oi; }
        }
        if (idx == lane) {
          unsigned ub = __float_as_uint(e);
          if (m) ub |= 0x80000000u;
          srow[round] = __uint_as_float(ub);
          e = BIG;
        }
      }
      if (lane == 0) cscr[grow * NSEG + eighth] = KSEL;
    }
  }
}

// ---- per-row merge of 8 segment-lists (<=256 candidates, 4 per lane) + loss
// epilogue. Standalone (r7 form) — NO device fences, NO completion counter:
// r9's fused last-block pattern (per-block __threadfence on 8 non-coherent
// XCD L2s) cost ~60 us, far more than the one launch it saved.
__global__ __launch_bounds__(256) void knn_merge(
    const float* __restrict__ scr, const int* __restrict__ cscr,
    const float* __restrict__ sqv, const int* __restrict__ tgt,
    const int* __restrict__ ccount, const int* __restrict__ j0a,
    const int* __restrict__ j1a, const float* __restrict__ X32,
    float* __restrict__ pacc) {
  __shared__ float blockAcc[4];
  const int tid = threadIdx.x;
  const int w = tid >> 6;
  const int lane = tid & 63;
  if (tid < 4) blockAcc[tid] = 0.0f;
  __syncthreads();
  for (int ri = 0; ri < 2; ri++) {
    const int grow = blockIdx.x * 8 + w * 2 + ri;
    const float* srow = scr + (size_t)grow * (NSEG * SEG);
    const int h = lane >> 5, li = lane & 31;
    float e[4]; int mm[4];
#pragma unroll
    for (int j = 0; j < 4; j++) {
      const int seg = j * 2 + h;
      const int cj = cscr[grow * NSEG + seg];
      if (li < cj) {
        unsigned u = __float_as_uint(srow[seg * SEG + li]);
        mm[j] = (int)(u >> 31); e[j] = __uint_as_float(u & 0x7fffffffu);
      } else { e[j] = BIG; mm[j] = 0; }
    }
    const float t17 = kth17_4(e[0], e[1], e[2], e[3]);
    float pls = 0.0f, nls = 0.0f; int cp = 0, cn = 0;
#pragma unroll
    for (int j = 0; j < 4; j++) {
      const bool s = (e[j] < t17);                        // strict, matches reference
      const float x = s ? expf(-sqrtf(fmaxf(e[j], 1e-12f))) : 0.0f;
      if (mm[j]) { pls += x; cp += (int)s; }
      else       { nls += x; cn += (int)s; }
    }
    int cpn = cp * 65536 + cn;
#pragma unroll
    for (int off = 32; off; off >>= 1) {
      pls += __shfl_xor(pls, off); nls += __shfl_xor(nls, off);
      cpn += __shfl_xor(cpn, off);
    }
    const int cpt = cpn >> 16, cnt_ = cpn & 0xffff;
    const int c = tgt[grow];
    const int ncl = ccount[c];
    const bool valid = (ncl > 1) && (ncl < NPTS);
    if (valid) {
      float pos_eff;
      if (cpt == 0) {
        const int jf = (grow == j0a[c]) ? j1a[c] : j0a[c];
        const float* xi = X32 + (size_t)grow * DIM;
        const float* xj = X32 + (size_t)jf * DIM;
        float pp = xi[lane] * xj[lane] + xi[lane + 64] * xj[lane + 64];
#pragma unroll
        for (int off = 32; off; off >>= 1) pp += __shfl_xor(pp, off);
        const float fb2 = sqv[grow] + sqv[jf] - 2.0f * pp;
        pos_eff = expf(-sqrtf(fmaxf(fb2, 1e-12f)));
      } else {
        pos_eff = pls;
      }
      if (lane == 0) {
        const float loss_i = -logf(pos_eff / (pos_eff + nls));
        const int cpa = (cpt == 0) ? 1 : cpt;
        atomicAdd(&blockAcc[0], loss_i);
        atomicAdd(&blockAcc[1], (cpa > cnt_) ? 1.0f : 0.0f);
        atomicAdd(&blockAcc[2], (float)cpt);
        atomicAdd(&blockAcc[3], (float)cnt_);
      }
    }
  }
  __syncthreads();
  if (tid < 4) pacc[blockIdx.x * 4 + tid] = blockAcc[tid];
}

// ---- final reduction: 1 block sums 1024 x 4 partials, writes out
__global__ void fin(const float* __restrict__ pacc, float* __restrict__ out) {
  __shared__ float red[256];
  const int tid = threadIdx.x;
  const int c = tid & 3, b0 = tid >> 2;
  float s = 0.0f;
  for (int b = b0; b < MBLK; b += 64) s += pacc[b * 4 + c];
  red[tid] = s;
  __syncthreads();
  if (tid < 4) {
    float t = 0.0f;
    for (int i = tid; i < 256; i += 4) t += red[i];
    out[tid] = t * (1.0f / (float)NPTS);
  }
}

extern "C" void kernel_launch(void* const* d_in, const int* in_sizes, int n_in,
                              void* d_out, int out_size, void* d_ws, size_t ws_size,
                              hipStream_t stream) {
  const float* X = (const float*)d_in[0];
  const long long* targets = (const long long*)d_in[1];
  float* out = (float*)d_out;

  char* ws = (char*)d_ws;
  unsigned short* Xb  = (unsigned short*)ws;                       // 2 MiB
  unsigned short* Xb2 = (unsigned short*)(ws + (2u << 20));        // 2 MiB (-2x)
  float* sqv    = (float*)   (ws + (4u << 20));                    // 32 KiB
  int*   tgt    = (int*)     (ws + (4u << 20) + (32u << 10));      // 32 KiB
  int*   ccount = (int*)     (ws + (4u << 20) + (64u << 10));      // 512 B
  int*   j0a    = (int*)     (ws + (4u << 20) + (65u << 10));      // 512 B
  int*   j1a    = (int*)     (ws + (4u << 20) + (66u << 10));      // 512 B
  float* pacc   = (float*)   (ws + (4u << 20) + (68u << 10));      // 16 KiB (1024 x 4)
  float* scr = (float*)(ws + (4u << 20) + (128u << 10));           // 8192*8*SEG*4 = 8 MiB
  int* cscr  = (int*)  (ws + (4u << 20) + (128u << 10) +
                        (size_t)NPTS * NSEG * SEG * 4);            // 256 KiB

  prep<<<2049, 256, 0, stream>>>(X, targets, Xb, Xb2, sqv, tgt, ccount, j0a, j1a);
  knn_main<<<1024, 256, 0, stream>>>(Xb, Xb2, sqv, tgt, scr, cscr);
  knn_merge<<<MBLK, 256, 0, stream>>>(scr, cscr, sqv, tgt, ccount, j0a, j1a, X, pacc);
  fin<<<1, 256, 0, stream>>>(pacc, out);
}